// Round 1
// baseline (1452.649 us; speedup 1.0000x reference)
//
#include <hip/hip_runtime.h>
#include <math.h>

// Problem constants
#define BATCH 16
#define CH    512
#define NTOK  1024            // H*W = 32*32
#define CHW   (CH * NTOK)     // 524288 elements per sample
#define EPSV  1e-5f

// Workspace layout (in floats):
//  [0,16)   per-sample sum
//  [16,32)  per-sample sumsq
//  [32,48)  mean
//  [48,64)  rstd
//  xn   : [64, 64 + 8388608)                       (B*C*N)   -- reused later for att_o
//  qkv  : next 25165824                            (B*3C*N)
//  S    : next 16777216                            (B*N*N)
static const size_t WS_XN   = 64;
static const size_t WS_QKV  = WS_XN + (size_t)BATCH * CH * NTOK;           // 8388672
static const size_t WS_S    = WS_QKV + (size_t)BATCH * 3 * CH * NTOK;      // 33554496
static const size_t WS_ATTO = WS_XN;  // xn dead after QKV GEMM

// ---------------- stats ----------------
__global__ void k_zero_stats(float* ws) {
    if (threadIdx.x < 64) ws[threadIdx.x] = 0.0f;
}

__global__ __launch_bounds__(256) void k_stats_partial(const float* __restrict__ x, float* __restrict__ ws) {
    int blk   = blockIdx.x;      // 16 samples * 64 chunks
    int b     = blk >> 6;
    int chunk = blk & 63;
    const float4* xp = (const float4*)(x + (size_t)b * CHW + (size_t)chunk * 8192);
    int t = threadIdx.x;
    float s = 0.0f, ss = 0.0f;
#pragma unroll
    for (int j = 0; j < 8; j++) {
        float4 v = xp[t + j * 256];
        s  += v.x + v.y + v.z + v.w;
        ss += v.x * v.x + v.y * v.y + v.z * v.z + v.w * v.w;
    }
#pragma unroll
    for (int off = 32; off; off >>= 1) {
        s  += __shfl_xor(s, off, 64);
        ss += __shfl_xor(ss, off, 64);
    }
    __shared__ float ls[4], lss[4];
    int wave = t >> 6, lane = t & 63;
    if (lane == 0) { ls[wave] = s; lss[wave] = ss; }
    __syncthreads();
    if (t == 0) {
        float S = ls[0] + ls[1] + ls[2] + ls[3];
        float SS = lss[0] + lss[1] + lss[2] + lss[3];
        atomicAdd(&ws[b], S);
        atomicAdd(&ws[16 + b], SS);
    }
}

__global__ void k_stats_final(float* ws) {
    int b = threadIdx.x;
    if (b < 16) {
        float inv  = 1.0f / (float)CHW;
        float mean = ws[b] * inv;
        float var  = ws[16 + b] * inv - mean * mean;
        ws[32 + b] = mean;
        ws[48 + b] = rsqrtf(var + EPSV);
    }
}

// ---------------- normalize ----------------
__global__ __launch_bounds__(256) void k_xn(const float* __restrict__ x,
                                            const float* __restrict__ nw,
                                            const float* __restrict__ nb,
                                            const float* __restrict__ ws,
                                            float* __restrict__ xn) {
    int f = blockIdx.x * 256 + threadIdx.x;     // float4 index, total 2097152
    int c = (f >> 8) & 511;
    int b = f >> 17;
    float mean = ws[32 + b], rstd = ws[48 + b];
    float a  = rstd * nw[c];
    float bb = nb[c] - mean * a;
    float4 v = ((const float4*)x)[f];
    float4 o;
    o.x = v.x * a + bb;
    o.y = v.y * a + bb;
    o.z = v.z * a + bb;
    o.w = v.w * a + bb;
    ((float4*)xn)[f] = o;
}

// ---------------- GEMM: qkv[b][o][n] = sum_c W[o][c]*xn[b][c][n] + bias[o] ----------------
__global__ __launch_bounds__(256) void k_gemm_qkv(const float* __restrict__ w,
                                                  const float* __restrict__ bias,
                                                  const float* __restrict__ xn,
                                                  float* __restrict__ qkv) {
    int b  = blockIdx.z;
    int n0 = blockIdx.x * 64;
    int o0 = blockIdx.y * 64;
    const float* X = xn + (size_t)b * CH * NTOK;
    float* D = qkv + (size_t)b * 3 * CH * NTOK;
    __shared__ float As[16][65];  // As[k][o] = W[o0+o][k0+k]
    __shared__ float Bs[16][65];  // Bs[k][n] = X[k0+k][n0+n]
    int t = threadIdx.x;
    int tx = t & 15, ty = t >> 4;
    float acc[4][4] = {};
    for (int k0 = 0; k0 < CH; k0 += 16) {
#pragma unroll
        for (int i = 0; i < 4; i++) {
            int p = t + i * 256;
            int o = p >> 4, k = p & 15;
            As[k][o] = w[(size_t)(o0 + o) * CH + k0 + k];
        }
#pragma unroll
        for (int i = 0; i < 4; i++) {
            int p = t + i * 256;
            int k = p >> 6, n = p & 63;
            Bs[k][n] = X[(size_t)(k0 + k) * NTOK + n0 + n];
        }
        __syncthreads();
#pragma unroll
        for (int k = 0; k < 16; k++) {
            float av[4], bv[4];
#pragma unroll
            for (int i = 0; i < 4; i++) av[i] = As[k][ty * 4 + i];
#pragma unroll
            for (int j = 0; j < 4; j++) bv[j] = Bs[k][tx * 4 + j];
#pragma unroll
            for (int i = 0; i < 4; i++)
#pragma unroll
                for (int j = 0; j < 4; j++) acc[i][j] += av[i] * bv[j];
        }
        __syncthreads();
    }
#pragma unroll
    for (int i = 0; i < 4; i++) {
        int o = o0 + ty * 4 + i;
        float bo = bias[o];
#pragma unroll
        for (int j = 0; j < 4; j++)
            D[(size_t)o * NTOK + n0 + tx * 4 + j] = acc[i][j] + bo;
    }
}

// ---------------- scores: S[b][n][m] = scale * sum_c Q[c][n]*K[c][m] ----------------
__global__ __launch_bounds__(256) void k_scores(const float* __restrict__ qkv, float* __restrict__ S) {
    int b  = blockIdx.z;
    int m0 = blockIdx.x * 64;
    int n0 = blockIdx.y * 64;
    const float* Q = qkv + (size_t)b * 3 * CH * NTOK;
    const float* K = Q + (size_t)CH * NTOK;
    float* Sb = S + (size_t)b * NTOK * NTOK;
    __shared__ float As[16][65];  // As[k][n]
    __shared__ float Bs[16][65];  // Bs[k][m]
    int t = threadIdx.x;
    int tx = t & 15, ty = t >> 4;
    float acc[4][4] = {};
    for (int k0 = 0; k0 < CH; k0 += 16) {
#pragma unroll
        for (int i = 0; i < 4; i++) {
            int p = t + i * 256;
            int k = p >> 6, n = p & 63;
            As[k][n] = Q[(size_t)(k0 + k) * NTOK + n0 + n];
        }
#pragma unroll
        for (int i = 0; i < 4; i++) {
            int p = t + i * 256;
            int k = p >> 6, m = p & 63;
            Bs[k][m] = K[(size_t)(k0 + k) * NTOK + m0 + m];
        }
        __syncthreads();
#pragma unroll
        for (int k = 0; k < 16; k++) {
            float av[4], bv[4];
#pragma unroll
            for (int i = 0; i < 4; i++) av[i] = As[k][ty * 4 + i];
#pragma unroll
            for (int j = 0; j < 4; j++) bv[j] = Bs[k][tx * 4 + j];
#pragma unroll
            for (int i = 0; i < 4; i++)
#pragma unroll
                for (int j = 0; j < 4; j++) acc[i][j] += av[i] * bv[j];
        }
        __syncthreads();
    }
    const float scale = 0.044194173824159216f;  // 512^-0.5
#pragma unroll
    for (int i = 0; i < 4; i++)
#pragma unroll
        for (int j = 0; j < 4; j++)
            Sb[(size_t)(n0 + ty * 4 + i) * NTOK + m0 + tx * 4 + j] = acc[i][j] * scale;
}

// ---------------- softmax over last axis, in place ----------------
__global__ __launch_bounds__(256) void k_softmax(float* __restrict__ S) {
    size_t row = blockIdx.x;
    float* p = S + row * NTOK;
    int t = threadIdx.x;
    int wave = t >> 6, lane = t & 63;
    __shared__ float red[4];
    float4 v = ((float4*)p)[t];
    float m = fmaxf(fmaxf(v.x, v.y), fmaxf(v.z, v.w));
#pragma unroll
    for (int off = 32; off; off >>= 1) m = fmaxf(m, __shfl_xor(m, off, 64));
    if (lane == 0) red[wave] = m;
    __syncthreads();
    m = fmaxf(fmaxf(red[0], red[1]), fmaxf(red[2], red[3]));
    __syncthreads();
    v.x = __expf(v.x - m);
    v.y = __expf(v.y - m);
    v.z = __expf(v.z - m);
    v.w = __expf(v.w - m);
    float s = v.x + v.y + v.z + v.w;
#pragma unroll
    for (int off = 32; off; off >>= 1) s += __shfl_xor(s, off, 64);
    if (lane == 0) red[wave] = s;
    __syncthreads();
    s = red[0] + red[1] + red[2] + red[3];
    float inv = 1.0f / s;
    v.x *= inv; v.y *= inv; v.z *= inv; v.w *= inv;
    ((float4*)p)[t] = v;
}

// ---------------- O[b][c][n] = sum_m V[c][m] * P[n][m] ----------------
__global__ __launch_bounds__(256) void k_av(const float* __restrict__ qkv,
                                            const float* __restrict__ P,
                                            float* __restrict__ O) {
    int b  = blockIdx.z;
    int n0 = blockIdx.x * 64;
    int c0 = blockIdx.y * 64;
    const float* V  = qkv + (size_t)b * 3 * CH * NTOK + 2 * (size_t)CH * NTOK;
    const float* Pb = P + (size_t)b * NTOK * NTOK;
    float* Ob = O + (size_t)b * CH * NTOK;
    __shared__ float As[16][65];  // As[k][c] = V[c0+c][m0+k]
    __shared__ float Bs[16][65];  // Bs[k][n] = P[n0+n][m0+k]
    int t = threadIdx.x;
    int tx = t & 15, ty = t >> 4;
    float acc[4][4] = {};
    for (int m0 = 0; m0 < NTOK; m0 += 16) {
#pragma unroll
        for (int i = 0; i < 4; i++) {
            int p = t + i * 256;
            int c = p >> 4, k = p & 15;
            As[k][c] = V[(size_t)(c0 + c) * NTOK + m0 + k];
        }
#pragma unroll
        for (int i = 0; i < 4; i++) {
            int p = t + i * 256;
            int n = p >> 4, k = p & 15;
            Bs[k][n] = Pb[(size_t)(n0 + n) * NTOK + m0 + k];
        }
        __syncthreads();
#pragma unroll
        for (int k = 0; k < 16; k++) {
            float av[4], bv[4];
#pragma unroll
            for (int i = 0; i < 4; i++) av[i] = As[k][ty * 4 + i];
#pragma unroll
            for (int j = 0; j < 4; j++) bv[j] = Bs[k][tx * 4 + j];
#pragma unroll
            for (int i = 0; i < 4; i++)
#pragma unroll
                for (int j = 0; j < 4; j++) acc[i][j] += av[i] * bv[j];
        }
        __syncthreads();
    }
#pragma unroll
    for (int i = 0; i < 4; i++)
#pragma unroll
        for (int j = 0; j < 4; j++)
            Ob[(size_t)(c0 + ty * 4 + i) * NTOK + n0 + tx * 4 + j] = acc[i][j];
}

// ---------------- out[b][o][n] = sum_c OW[o][c]*O[b][c][n] + ob[o] + x[b][o][n] ----------------
__global__ __launch_bounds__(256) void k_proj(const float* __restrict__ ow,
                                              const float* __restrict__ ob,
                                              const float* __restrict__ O,
                                              const float* __restrict__ x,
                                              float* __restrict__ out) {
    int b  = blockIdx.z;
    int n0 = blockIdx.x * 64;
    int o0 = blockIdx.y * 64;
    const float* Ob = O + (size_t)b * CH * NTOK;
    const float* xb = x + (size_t)b * CH * NTOK;
    float* outb = out + (size_t)b * CH * NTOK;
    __shared__ float As[16][65];  // As[k][o] = OW[o0+o][k0+k]
    __shared__ float Bs[16][65];  // Bs[k][n] = O[k0+k][n0+n]
    int t = threadIdx.x;
    int tx = t & 15, ty = t >> 4;
    float acc[4][4] = {};
    for (int k0 = 0; k0 < CH; k0 += 16) {
#pragma unroll
        for (int i = 0; i < 4; i++) {
            int p = t + i * 256;
            int o = p >> 4, k = p & 15;
            As[k][o] = ow[(size_t)(o0 + o) * CH + k0 + k];
        }
#pragma unroll
        for (int i = 0; i < 4; i++) {
            int p = t + i * 256;
            int k = p >> 6, n = p & 63;
            Bs[k][n] = Ob[(size_t)(k0 + k) * NTOK + n0 + n];
        }
        __syncthreads();
#pragma unroll
        for (int k = 0; k < 16; k++) {
            float av[4], bv[4];
#pragma unroll
            for (int i = 0; i < 4; i++) av[i] = As[k][ty * 4 + i];
#pragma unroll
            for (int j = 0; j < 4; j++) bv[j] = Bs[k][tx * 4 + j];
#pragma unroll
            for (int i = 0; i < 4; i++)
#pragma unroll
                for (int j = 0; j < 4; j++) acc[i][j] += av[i] * bv[j];
        }
        __syncthreads();
    }
#pragma unroll
    for (int i = 0; i < 4; i++) {
        int o = o0 + ty * 4 + i;
        float bo = ob[o];
#pragma unroll
        for (int j = 0; j < 4; j++) {
            size_t idx = (size_t)o * NTOK + n0 + tx * 4 + j;
            outb[idx] = acc[i][j] + bo + xb[idx];
        }
    }
}

extern "C" void kernel_launch(void* const* d_in, const int* in_sizes, int n_in,
                              void* d_out, int out_size, void* d_ws, size_t ws_size,
                              hipStream_t stream) {
    const float* x      = (const float*)d_in[0];
    const float* norm_w = (const float*)d_in[1];
    const float* norm_b = (const float*)d_in[2];
    const float* qkv_w  = (const float*)d_in[3];
    const float* qkv_b  = (const float*)d_in[4];
    const float* out_w  = (const float*)d_in[5];
    const float* out_b  = (const float*)d_in[6];
    float* out = (float*)d_out;
    float* ws  = (float*)d_ws;

    float* xn   = ws + WS_XN;
    float* qkv  = ws + WS_QKV;
    float* S    = ws + WS_S;
    float* atto = ws + WS_ATTO;  // reuse of xn buffer

    k_zero_stats<<<1, 64, 0, stream>>>(ws);
    k_stats_partial<<<BATCH * 64, 256, 0, stream>>>(x, ws);
    k_stats_final<<<1, 16, 0, stream>>>(ws);
    k_xn<<<(BATCH * CH * NTOK / 4) / 256, 256, 0, stream>>>(x, norm_w, norm_b, ws, xn);
    k_gemm_qkv<<<dim3(NTOK / 64, 3 * CH / 64, BATCH), 256, 0, stream>>>(qkv_w, qkv_b, xn, qkv);
    k_scores<<<dim3(NTOK / 64, NTOK / 64, BATCH), 256, 0, stream>>>(qkv, S);
    k_softmax<<<BATCH * NTOK, 256, 0, stream>>>(S);
    k_av<<<dim3(NTOK / 64, CH / 64, BATCH), 256, 0, stream>>>(qkv, S, atto);
    k_proj<<<dim3(NTOK / 64, CH / 64, BATCH), 256, 0, stream>>>(out_w, out_b, atto, x, out);
}

// Round 2
// 279.357 us; speedup vs baseline: 5.2000x; 5.2000x over previous
//
#include <hip/hip_runtime.h>
#include <math.h>

#define BATCH 16
#define CH    512
#define NTOK  1024
#define CHW   (CH * NTOK)
#define EPSV  1e-5f

typedef __attribute__((ext_vector_type(8))) short bf16x8;
typedef __attribute__((ext_vector_type(4))) float f32x4;

__device__ __forceinline__ unsigned short f2bf(float f) {
    union { float f; unsigned u; } cv; cv.f = f;
    unsigned r = cv.u + 0x7FFFu + ((cv.u >> 16) & 1u);   // round-to-nearest-even
    return (unsigned short)(r >> 16);
}

// ---------------- workspace layout (byte offsets) ----------------
// stats: 64 floats at 0
static const size_t OFF_WQKV = 256;                       // 1536*512 bf16
static const size_t OFF_OW   = OFF_WQKV + 1572864;        // 512*512 bf16
static const size_t OFF_XNT  = OFF_OW   + 524288;         // B*N*C bf16  (xn, token-major)
static const size_t OFF_QT   = OFF_XNT  + 16777216;       // B*N*C bf16  (Q token-major)
static const size_t OFF_KT   = OFF_QT   + 16777216;       // B*N*C bf16  (K token-major)
static const size_t OFF_V    = OFF_KT   + 16777216;       // B*C*N bf16  (V channel-major)
static const size_t OFF_OT   = OFF_V    + 16777216;       // B*N*C bf16  (attn out token-major)
static const size_t OFF_S    = OFF_OT   + 16777216;       // B*N*N f32
static const size_t OFF_P    = OFF_S    + 67108864;       // B*N*N bf16
// end = 186646784 bytes (~187 MB)

// ---------------- stats ----------------
__global__ void k_zero_stats(float* ws) {
    if (threadIdx.x < 64) ws[threadIdx.x] = 0.0f;
}

__global__ __launch_bounds__(256) void k_stats_partial(const float* __restrict__ x, float* __restrict__ ws) {
    int blk   = blockIdx.x;
    int b     = blk >> 6;
    int chunk = blk & 63;
    const float4* xp = (const float4*)(x + (size_t)b * CHW + (size_t)chunk * 8192);
    int t = threadIdx.x;
    float s = 0.0f, ss = 0.0f;
#pragma unroll
    for (int j = 0; j < 8; j++) {
        float4 v = xp[t + j * 256];
        s  += v.x + v.y + v.z + v.w;
        ss += v.x * v.x + v.y * v.y + v.z * v.z + v.w * v.w;
    }
#pragma unroll
    for (int off = 32; off; off >>= 1) {
        s  += __shfl_xor(s, off, 64);
        ss += __shfl_xor(ss, off, 64);
    }
    __shared__ float ls[4], lss[4];
    int wave = t >> 6, lane = t & 63;
    if (lane == 0) { ls[wave] = s; lss[wave] = ss; }
    __syncthreads();
    if (t == 0) {
        atomicAdd(&ws[b], ls[0] + ls[1] + ls[2] + ls[3]);
        atomicAdd(&ws[16 + b], lss[0] + lss[1] + lss[2] + lss[3]);
    }
}

__global__ void k_stats_final(float* ws) {
    int b = threadIdx.x;
    if (b < 16) {
        float inv  = 1.0f / (float)CHW;
        float mean = ws[b] * inv;
        float var  = ws[16 + b] * inv - mean * mean;
        ws[32 + b] = mean;
        ws[48 + b] = rsqrtf(var + EPSV);
    }
}

// ---------------- weight f32 -> bf16 convert ----------------
__global__ __launch_bounds__(256) void k_cvt(const float* __restrict__ in, unsigned short* __restrict__ out, int n4) {
    int i = blockIdx.x * 256 + threadIdx.x;
    if (i < n4) {
        float4 v = ((const float4*)in)[i];
        ushort4 o;
        o.x = f2bf(v.x); o.y = f2bf(v.y); o.z = f2bf(v.z); o.w = f2bf(v.w);
        ((ushort4*)out)[i] = o;
    }
}

// ---------------- normalize + transpose -> xn_t[b][n][c] bf16 ----------------
__global__ __launch_bounds__(256) void k_xnt(const float* __restrict__ x,
                                             const float* __restrict__ nw,
                                             const float* __restrict__ nb,
                                             const float* __restrict__ ws,
                                             unsigned short* __restrict__ xnt) {
    __shared__ float ls[64][65];
    int b  = blockIdx.z;
    int c0 = blockIdx.y * 64;
    int n0 = blockIdx.x * 64;
    float mean = ws[32 + b], rstd = ws[48 + b];
    int t = threadIdx.x;
    int cl = t >> 4, n4 = t & 15;
    const float* xb = x + (size_t)b * CHW;
#pragma unroll
    for (int i = 0; i < 4; i++) {
        int c = c0 + cl + i * 16;
        float a  = rstd * nw[c];
        float bb = nb[c] - mean * a;
        float4 v = *(const float4*)(xb + (size_t)c * NTOK + n0 + n4 * 4);
        ls[cl + i * 16][n4 * 4 + 0] = v.x * a + bb;
        ls[cl + i * 16][n4 * 4 + 1] = v.y * a + bb;
        ls[cl + i * 16][n4 * 4 + 2] = v.z * a + bb;
        ls[cl + i * 16][n4 * 4 + 3] = v.w * a + bb;
    }
    __syncthreads();
    int nl = t >> 4, c4 = t & 15;
    unsigned short* dst = xnt + (size_t)b * NTOK * CH;
#pragma unroll
    for (int i = 0; i < 4; i++) {
        int n = n0 + nl + i * 16;
        ushort4 o;
        o.x = f2bf(ls[c4 * 4 + 0][nl + i * 16]);
        o.y = f2bf(ls[c4 * 4 + 1][nl + i * 16]);
        o.z = f2bf(ls[c4 * 4 + 2][nl + i * 16]);
        o.w = f2bf(ls[c4 * 4 + 3][nl + i * 16]);
        *(ushort4*)(dst + (size_t)n * CH + c0 + c4 * 4) = o;
    }
}

// ---------------- MFMA GEMM core ----------------
// D[m][n] = sum_k A[m][k] * B[n][k]   (both operands k-contiguous, bf16)
// block: 256 threads = 4 waves, 128x128 tile, per-wave 64x64 via 4x4 16x16x32 MFMAs
__device__ __forceinline__ void mfma_core(const unsigned short* __restrict__ A, int lda,
                                          const unsigned short* __restrict__ B, int ldb,
                                          int K, int m0, int n0,
                                          unsigned short* sA, unsigned short* sB,
                                          f32x4 acc[4][4]) {
    const int t = threadIdx.x;
    const int w = t >> 6, lane = t & 63;
    const int wm = (w & 1) * 64, wn = (w >> 1) * 64;
    const int r16 = lane & 15, quad = lane >> 4;
#pragma unroll
    for (int i = 0; i < 4; i++)
#pragma unroll
        for (int j = 0; j < 4; j++) acc[i][j] = (f32x4){0.f, 0.f, 0.f, 0.f};
    const int row0 = t >> 2, kc0 = (t & 3) * 8;
    for (int k0 = 0; k0 < K; k0 += 32) {
        *(uint4*)(sA + (row0)      * 32 + kc0) = *(const uint4*)(A + (size_t)(m0 + row0)      * lda + k0 + kc0);
        *(uint4*)(sA + (row0 + 64) * 32 + kc0) = *(const uint4*)(A + (size_t)(m0 + row0 + 64) * lda + k0 + kc0);
        *(uint4*)(sB + (row0)      * 32 + kc0) = *(const uint4*)(B + (size_t)(n0 + row0)      * ldb + k0 + kc0);
        *(uint4*)(sB + (row0 + 64) * 32 + kc0) = *(const uint4*)(B + (size_t)(n0 + row0 + 64) * ldb + k0 + kc0);
        __syncthreads();
        bf16x8 af[4], bfr[4];
#pragma unroll
        for (int i = 0; i < 4; i++) af[i]  = *(const bf16x8*)(sA + (wm + i * 16 + r16) * 32 + quad * 8);
#pragma unroll
        for (int j = 0; j < 4; j++) bfr[j] = *(const bf16x8*)(sB + (wn + j * 16 + r16) * 32 + quad * 8);
#pragma unroll
        for (int i = 0; i < 4; i++)
#pragma unroll
            for (int j = 0; j < 4; j++)
                acc[i][j] = __builtin_amdgcn_mfma_f32_16x16x32_bf16(af[i], bfr[j], acc[i][j], 0, 0, 0);
        __syncthreads();
    }
}

// ---------------- GEMM1: qkv = Wqkv * xn ----------------
// D[o][n] = sum_c W[o][c] * XNT[n][c] + qb[o]; store Q,K token-major, V channel-major
__global__ __launch_bounds__(256) void k_gemm_qkv(const unsigned short* __restrict__ Wq,
                                                  const float* __restrict__ qb,
                                                  const unsigned short* __restrict__ XNT,
                                                  unsigned short* __restrict__ QT,
                                                  unsigned short* __restrict__ KT,
                                                  unsigned short* __restrict__ V) {
    __shared__ __align__(16) unsigned short sA[128 * 32];
    __shared__ __align__(16) unsigned short sB[128 * 32];
    const int b  = blockIdx.z;
    const int m0 = blockIdx.y * 128;  // o in [0,1536)
    const int n0 = blockIdx.x * 128;  // n
    f32x4 acc[4][4];
    mfma_core(Wq, CH, XNT + (size_t)b * NTOK * CH, CH, CH, m0, n0, sA, sB, acc);
    const int t = threadIdx.x;
    const int w = t >> 6, lane = t & 63;
    const int wm = (w & 1) * 64, wn = (w >> 1) * 64;
    const int r16 = lane & 15, quad = lane >> 4;
    const int region = m0 >> 9;  // 0=Q 1=K 2=V (block-uniform: 128 | 512)
    unsigned short* dstT = (region == 0) ? QT : KT;
#pragma unroll
    for (int i = 0; i < 4; i++) {
        const int o0g = m0 + wm + i * 16 + quad * 4;
        const int ro  = o0g & 511;
#pragma unroll
        for (int j = 0; j < 4; j++) {
            const int col = n0 + wn + j * 16 + r16;   // n
            f32x4 a = acc[i][j];
            if (region < 2) {
                ushort4 pk;
                pk.x = f2bf(a[0] + qb[o0g + 0]);
                pk.y = f2bf(a[1] + qb[o0g + 1]);
                pk.z = f2bf(a[2] + qb[o0g + 2]);
                pk.w = f2bf(a[3] + qb[o0g + 3]);
                *(ushort4*)(dstT + (size_t)b * NTOK * CH + (size_t)col * CH + ro) = pk;
            } else {
#pragma unroll
                for (int r = 0; r < 4; r++)
                    V[(size_t)b * CH * NTOK + (size_t)(ro + r) * NTOK + col] = f2bf(a[r] + qb[o0g + r]);
            }
        }
    }
}

// ---------------- GEMM2: S[n][m] = scale * sum_c Q[n][c] * K[m][c] ----------------
__global__ __launch_bounds__(256) void k_gemm_sc(const unsigned short* __restrict__ QT,
                                                 const unsigned short* __restrict__ KT,
                                                 float* __restrict__ S) {
    __shared__ __align__(16) unsigned short sA[128 * 32];
    __shared__ __align__(16) unsigned short sB[128 * 32];
    const int b  = blockIdx.z;
    const int m0 = blockIdx.y * 128;  // n
    const int n0 = blockIdx.x * 128;  // m
    f32x4 acc[4][4];
    mfma_core(QT + (size_t)b * NTOK * CH, CH, KT + (size_t)b * NTOK * CH, CH, CH, m0, n0, sA, sB, acc);
    const int t = threadIdx.x;
    const int w = t >> 6, lane = t & 63;
    const int wm = (w & 1) * 64, wn = (w >> 1) * 64;
    const int r16 = lane & 15, quad = lane >> 4;
    const float scale = 0.044194173824159216f;  // 512^-0.5
    float* Sb = S + (size_t)b * NTOK * NTOK;
#pragma unroll
    for (int i = 0; i < 4; i++) {
        const int row0 = m0 + wm + i * 16 + quad * 4;
#pragma unroll
        for (int j = 0; j < 4; j++) {
            const int col = n0 + wn + j * 16 + r16;
            f32x4 a = acc[i][j];
#pragma unroll
            for (int r = 0; r < 4; r++)
                Sb[(size_t)(row0 + r) * NTOK + col] = a[r] * scale;
        }
    }
}

// ---------------- softmax: S f32 row -> P bf16 row ----------------
__global__ __launch_bounds__(256) void k_softmax(const float* __restrict__ S, unsigned short* __restrict__ P) {
    size_t row = blockIdx.x;
    const float* p = S + row * NTOK;
    unsigned short* q = P + row * NTOK;
    int t = threadIdx.x;
    int wave = t >> 6, lane = t & 63;
    __shared__ float red[4];
    float4 v = ((const float4*)p)[t];
    float m = fmaxf(fmaxf(v.x, v.y), fmaxf(v.z, v.w));
#pragma unroll
    for (int off = 32; off; off >>= 1) m = fmaxf(m, __shfl_xor(m, off, 64));
    if (lane == 0) red[wave] = m;
    __syncthreads();
    m = fmaxf(fmaxf(red[0], red[1]), fmaxf(red[2], red[3]));
    __syncthreads();
    v.x = __expf(v.x - m);
    v.y = __expf(v.y - m);
    v.z = __expf(v.z - m);
    v.w = __expf(v.w - m);
    float s = v.x + v.y + v.z + v.w;
#pragma unroll
    for (int off = 32; off; off >>= 1) s += __shfl_xor(s, off, 64);
    if (lane == 0) red[wave] = s;
    __syncthreads();
    s = red[0] + red[1] + red[2] + red[3];
    float inv = 1.0f / s;
    ushort4 o;
    o.x = f2bf(v.x * inv); o.y = f2bf(v.y * inv); o.z = f2bf(v.z * inv); o.w = f2bf(v.w * inv);
    ((ushort4*)q)[t] = o;
}

// ---------------- GEMM3: O[c][n] = sum_m V[c][m] * P[n][m]; store O_t[n][c] bf16 ----------------
__global__ __launch_bounds__(256) void k_gemm_av(const unsigned short* __restrict__ V,
                                                 const unsigned short* __restrict__ P,
                                                 unsigned short* __restrict__ OT) {
    __shared__ __align__(16) unsigned short sA[128 * 32];
    __shared__ __align__(16) unsigned short sB[128 * 32];
    const int b  = blockIdx.z;
    const int m0 = blockIdx.y * 128;  // c in [0,512)
    const int n0 = blockIdx.x * 128;  // n
    f32x4 acc[4][4];
    mfma_core(V + (size_t)b * CH * NTOK, NTOK, P + (size_t)b * NTOK * NTOK, NTOK, NTOK, m0, n0, sA, sB, acc);
    const int t = threadIdx.x;
    const int w = t >> 6, lane = t & 63;
    const int wm = (w & 1) * 64, wn = (w >> 1) * 64;
    const int r16 = lane & 15, quad = lane >> 4;
    unsigned short* OTb = OT + (size_t)b * NTOK * CH;
#pragma unroll
    for (int i = 0; i < 4; i++) {
        const int c0g = m0 + wm + i * 16 + quad * 4;
#pragma unroll
        for (int j = 0; j < 4; j++) {
            const int col = n0 + wn + j * 16 + r16;   // n
            f32x4 a = acc[i][j];
            ushort4 pk;
            pk.x = f2bf(a[0]); pk.y = f2bf(a[1]); pk.z = f2bf(a[2]); pk.w = f2bf(a[3]);
            *(ushort4*)(OTb + (size_t)col * CH + c0g) = pk;
        }
    }
}

// ---------------- GEMM4: out[o][n] = sum_c OW[o][c]*O_t[n][c] + ob[o] + x ----------------
__global__ __launch_bounds__(256) void k_gemm_out(const unsigned short* __restrict__ OW,
                                                  const float* __restrict__ ob,
                                                  const unsigned short* __restrict__ OT,
                                                  const float* __restrict__ x,
                                                  float* __restrict__ out) {
    __shared__ __align__(16) unsigned short sA[128 * 32];
    __shared__ __align__(16) unsigned short sB[128 * 32];
    const int b  = blockIdx.z;
    const int m0 = blockIdx.y * 128;  // o in [0,512)
    const int n0 = blockIdx.x * 128;  // n
    f32x4 acc[4][4];
    mfma_core(OW, CH, OT + (size_t)b * NTOK * CH, CH, CH, m0, n0, sA, sB, acc);
    const int t = threadIdx.x;
    const int w = t >> 6, lane = t & 63;
    const int wm = (w & 1) * 64, wn = (w >> 1) * 64;
    const int r16 = lane & 15, quad = lane >> 4;
#pragma unroll
    for (int i = 0; i < 4; i++) {
        const int o0g = m0 + wm + i * 16 + quad * 4;
#pragma unroll
        for (int j = 0; j < 4; j++) {
            const int col = n0 + wn + j * 16 + r16;
            f32x4 a = acc[i][j];
#pragma unroll
            for (int r = 0; r < 4; r++) {
                size_t idx = (size_t)b * CHW + (size_t)(o0g + r) * NTOK + col;
                out[idx] = a[r] + ob[o0g + r] + x[idx];
            }
        }
    }
}

extern "C" void kernel_launch(void* const* d_in, const int* in_sizes, int n_in,
                              void* d_out, int out_size, void* d_ws, size_t ws_size,
                              hipStream_t stream) {
    const float* x      = (const float*)d_in[0];
    const float* norm_w = (const float*)d_in[1];
    const float* norm_b = (const float*)d_in[2];
    const float* qkv_w  = (const float*)d_in[3];
    const float* qkv_b  = (const float*)d_in[4];
    const float* out_w  = (const float*)d_in[5];
    const float* out_b  = (const float*)d_in[6];
    float* out = (float*)d_out;
    char* wsb  = (char*)d_ws;

    float* stats = (float*)wsb;
    unsigned short* WQ  = (unsigned short*)(wsb + OFF_WQKV);
    unsigned short* OW  = (unsigned short*)(wsb + OFF_OW);
    unsigned short* XNT = (unsigned short*)(wsb + OFF_XNT);
    unsigned short* QT  = (unsigned short*)(wsb + OFF_QT);
    unsigned short* KT  = (unsigned short*)(wsb + OFF_KT);
    unsigned short* V   = (unsigned short*)(wsb + OFF_V);
    unsigned short* OT  = (unsigned short*)(wsb + OFF_OT);
    float*          S   = (float*)(wsb + OFF_S);
    unsigned short* P   = (unsigned short*)(wsb + OFF_P);

    k_zero_stats<<<1, 64, 0, stream>>>(stats);
    k_stats_partial<<<BATCH * 64, 256, 0, stream>>>(x, stats);
    k_stats_final<<<1, 16, 0, stream>>>(stats);
    k_cvt<<<768, 256, 0, stream>>>(qkv_w, WQ, 3 * CH * CH / 4);
    k_cvt<<<256, 256, 0, stream>>>(out_w, OW, CH * CH / 4);
    k_xnt<<<dim3(NTOK / 64, CH / 64, BATCH), 256, 0, stream>>>(x, norm_w, norm_b, stats, XNT);
    k_gemm_qkv<<<dim3(NTOK / 128, 3 * CH / 128, BATCH), 256, 0, stream>>>(WQ, qkv_b, XNT, QT, KT, V);
    k_gemm_sc<<<dim3(NTOK / 128, NTOK / 128, BATCH), 256, 0, stream>>>(QT, KT, S);
    k_softmax<<<BATCH * NTOK, 256, 0, stream>>>(S, P);
    k_gemm_av<<<dim3(NTOK / 128, CH / 128, BATCH), 256, 0, stream>>>(V, P, OT);
    k_gemm_out<<<dim3(NTOK / 128, CH / 128, BATCH), 256, 0, stream>>>(OW, out_b, OT, x, out);
}

// Round 3
// 266.193 us; speedup vs baseline: 5.4571x; 1.0495x over previous
//
#include <hip/hip_runtime.h>
#include <math.h>

#define BATCH 16
#define CH    512
#define NTOK  1024
#define CHW   (CH * NTOK)
#define EPSV  1e-5f

typedef __attribute__((ext_vector_type(8))) short bf16x8;
typedef __attribute__((ext_vector_type(4))) float f32x4;

__device__ __forceinline__ unsigned short f2bf(float f) {
    union { float f; unsigned u; } cv; cv.f = f;
    unsigned r = cv.u + 0x7FFFu + ((cv.u >> 16) & 1u);   // round-to-nearest-even
    return (unsigned short)(r >> 16);
}
__device__ __forceinline__ float bf2f(unsigned short u) {
    union { unsigned u; float f; } cv; cv.u = ((unsigned)u) << 16;
    return cv.f;
}

// async global -> LDS, 16 bytes per lane. LDS dest is wave-uniform base + lane*16.
__device__ __forceinline__ void async16(const unsigned short* g, unsigned short* l) {
    __builtin_amdgcn_global_load_lds(
        (const __attribute__((address_space(1))) void*)g,
        (__attribute__((address_space(3))) void*)l,
        16, 0, 0);
}

// ---------------- workspace layout (byte offsets) ----------------
static const size_t OFF_WQKV = 256;                        // 1536*512 bf16
static const size_t OFF_OW   = OFF_WQKV + 1572864;         // 512*512 bf16
static const size_t OFF_XNT  = OFF_OW   + 524288;          // B*N*C bf16 (xn token-major)
static const size_t OFF_QT   = OFF_XNT  + 16777216;        // B*N*C bf16
static const size_t OFF_KT   = OFF_QT   + 16777216;        // B*N*C bf16
static const size_t OFF_V    = OFF_KT   + 16777216;        // B*C*N bf16 (channel-major)
static const size_t OFF_OT   = OFF_V    + 16777216;        // B*N*C bf16
static const size_t OFF_S    = OFF_OT   + 16777216;        // B*N*N bf16 (scores)
static const size_t OFF_P    = OFF_S    + 33554432;        // B*N*N bf16 (probs)
// end = 153092352 bytes (~153 MB)

// ---------------- stats ----------------
__global__ void k_zero_stats(float* ws) {
    if (threadIdx.x < 64) ws[threadIdx.x] = 0.0f;
}

__global__ __launch_bounds__(256) void k_stats_partial(const float* __restrict__ x, float* __restrict__ ws) {
    int blk   = blockIdx.x;
    int b     = blk >> 6;
    int chunk = blk & 63;
    const float4* xp = (const float4*)(x + (size_t)b * CHW + (size_t)chunk * 8192);
    int t = threadIdx.x;
    float s = 0.0f, ss = 0.0f;
#pragma unroll
    for (int j = 0; j < 8; j++) {
        float4 v = xp[t + j * 256];
        s  += v.x + v.y + v.z + v.w;
        ss += v.x * v.x + v.y * v.y + v.z * v.z + v.w * v.w;
    }
#pragma unroll
    for (int off = 32; off; off >>= 1) {
        s  += __shfl_xor(s, off, 64);
        ss += __shfl_xor(ss, off, 64);
    }
    __shared__ float ls[4], lss[4];
    int wave = t >> 6, lane = t & 63;
    if (lane == 0) { ls[wave] = s; lss[wave] = ss; }
    __syncthreads();
    if (t == 0) {
        atomicAdd(&ws[b], ls[0] + ls[1] + ls[2] + ls[3]);
        atomicAdd(&ws[16 + b], lss[0] + lss[1] + lss[2] + lss[3]);
    }
}

__global__ void k_stats_final(float* ws) {
    int b = threadIdx.x;
    if (b < 16) {
        float inv  = 1.0f / (float)CHW;
        float mean = ws[b] * inv;
        float var  = ws[16 + b] * inv - mean * mean;
        ws[32 + b] = mean;
        ws[48 + b] = rsqrtf(var + EPSV);
    }
}

// ---------------- weight f32 -> bf16 ----------------
__global__ __launch_bounds__(256) void k_cvt(const float* __restrict__ in, unsigned short* __restrict__ out, int n4) {
    int i = blockIdx.x * 256 + threadIdx.x;
    if (i < n4) {
        float4 v = ((const float4*)in)[i];
        ushort4 o;
        o.x = f2bf(v.x); o.y = f2bf(v.y); o.z = f2bf(v.z); o.w = f2bf(v.w);
        ((ushort4*)out)[i] = o;
    }
}

// ---------------- normalize + transpose -> xn_t[b][n][c] bf16 ----------------
__global__ __launch_bounds__(256) void k_xnt(const float* __restrict__ x,
                                             const float* __restrict__ nw,
                                             const float* __restrict__ nb,
                                             const float* __restrict__ ws,
                                             unsigned short* __restrict__ xnt) {
    __shared__ float ls[64][65];
    int b  = blockIdx.z;
    int c0 = blockIdx.y * 64;
    int n0 = blockIdx.x * 64;
    float mean = ws[32 + b], rstd = ws[48 + b];
    int t = threadIdx.x;
    int cl = t >> 4, n4 = t & 15;
    const float* xb = x + (size_t)b * CHW;
#pragma unroll
    for (int i = 0; i < 4; i++) {
        int c = c0 + cl + i * 16;
        float a  = rstd * nw[c];
        float bb = nb[c] - mean * a;
        float4 v = *(const float4*)(xb + (size_t)c * NTOK + n0 + n4 * 4);
        ls[cl + i * 16][n4 * 4 + 0] = v.x * a + bb;
        ls[cl + i * 16][n4 * 4 + 1] = v.y * a + bb;
        ls[cl + i * 16][n4 * 4 + 2] = v.z * a + bb;
        ls[cl + i * 16][n4 * 4 + 3] = v.w * a + bb;
    }
    __syncthreads();
    int nl = t >> 4, c4 = t & 15;
    unsigned short* dst = xnt + (size_t)b * NTOK * CH;
#pragma unroll
    for (int i = 0; i < 4; i++) {
        int n = n0 + nl + i * 16;
        ushort4 o;
        o.x = f2bf(ls[c4 * 4 + 0][nl + i * 16]);
        o.y = f2bf(ls[c4 * 4 + 1][nl + i * 16]);
        o.z = f2bf(ls[c4 * 4 + 2][nl + i * 16]);
        o.w = f2bf(ls[c4 * 4 + 3][nl + i * 16]);
        *(ushort4*)(dst + (size_t)n * CH + c0 + c4 * 4) = o;
    }
}

// ---------------- MFMA GEMM core with async LDS staging ----------------
// D[m][n] = sum_k A[m][k] * B[n][k]  (both k-contiguous bf16)
// 256 thr = 4 waves, 128x128 tile, BK=32; wave w stages rows [w*32, w*32+32)
__device__ __forceinline__ void mfma_core(const unsigned short* __restrict__ A, int lda,
                                          const unsigned short* __restrict__ B, int ldb,
                                          int K, int m0, int n0,
                                          unsigned short* sA, unsigned short* sB,
                                          f32x4 acc[4][4]) {
    const int t = threadIdx.x;
    const int w = t >> 6, lane = t & 63;
    const int wm = (w & 1) * 64, wn = (w >> 1) * 64;
    const int r16 = lane & 15, quad = lane >> 4;
#pragma unroll
    for (int i = 0; i < 4; i++)
#pragma unroll
        for (int j = 0; j < 4; j++) acc[i][j] = (f32x4){0.f, 0.f, 0.f, 0.f};
    const int sr = lane >> 2;           // row within 16-row chunk
    const int sk = (lane & 3) * 8;      // k element offset (16B)
    const unsigned short* gA0 = A + (size_t)(m0 + w * 32 + sr) * lda + sk;
    const unsigned short* gA1 = gA0 + (size_t)16 * lda;
    const unsigned short* gB0 = B + (size_t)(n0 + w * 32 + sr) * ldb + sk;
    const unsigned short* gB1 = gB0 + (size_t)16 * ldb;
    unsigned short* lA0 = sA + (w * 32)      * 32;
    unsigned short* lA1 = sA + (w * 32 + 16) * 32;
    unsigned short* lB0 = sB + (w * 32)      * 32;
    unsigned short* lB1 = sB + (w * 32 + 16) * 32;
    for (int k0 = 0; k0 < K; k0 += 32) {
        async16(gA0 + k0, lA0);
        async16(gA1 + k0, lA1);
        async16(gB0 + k0, lB0);
        async16(gB1 + k0, lB1);
        __syncthreads();
        bf16x8 af[4], bfr[4];
#pragma unroll
        for (int i = 0; i < 4; i++) af[i]  = *(const bf16x8*)(sA + (wm + i * 16 + r16) * 32 + quad * 8);
#pragma unroll
        for (int j = 0; j < 4; j++) bfr[j] = *(const bf16x8*)(sB + (wn + j * 16 + r16) * 32 + quad * 8);
#pragma unroll
        for (int i = 0; i < 4; i++)
#pragma unroll
            for (int j = 0; j < 4; j++)
                acc[i][j] = __builtin_amdgcn_mfma_f32_16x16x32_bf16(af[i], bfr[j], acc[i][j], 0, 0, 0);
        __syncthreads();
    }
}

// ---------------- GEMM1: qkv ----------------
__global__ __launch_bounds__(256) void k_gemm_qkv(const unsigned short* __restrict__ Wq,
                                                  const float* __restrict__ qb,
                                                  const unsigned short* __restrict__ XNT,
                                                  unsigned short* __restrict__ QT,
                                                  unsigned short* __restrict__ KT,
                                                  unsigned short* __restrict__ V) {
    __shared__ __align__(16) unsigned short sA[128 * 32];
    __shared__ __align__(16) unsigned short sB[128 * 32];
    const int b  = blockIdx.z;
    const int m0 = blockIdx.y * 128;  // o in [0,1536)
    const int n0 = blockIdx.x * 128;  // n
    f32x4 acc[4][4];
    mfma_core(Wq, CH, XNT + (size_t)b * NTOK * CH, CH, CH, m0, n0, sA, sB, acc);
    const int t = threadIdx.x;
    const int w = t >> 6, lane = t & 63;
    const int wm = (w & 1) * 64, wn = (w >> 1) * 64;
    const int r16 = lane & 15, quad = lane >> 4;
    const int region = m0 >> 9;  // 0=Q 1=K 2=V (block-uniform)
    unsigned short* dstT = (region == 0) ? QT : KT;
#pragma unroll
    for (int i = 0; i < 4; i++) {
        const int o0g = m0 + wm + i * 16 + quad * 4;
        const int ro  = o0g & 511;
#pragma unroll
        for (int j = 0; j < 4; j++) {
            const int col = n0 + wn + j * 16 + r16;   // n
            f32x4 a = acc[i][j];
            if (region < 2) {
                ushort4 pk;
                pk.x = f2bf(a[0] + qb[o0g + 0]);
                pk.y = f2bf(a[1] + qb[o0g + 1]);
                pk.z = f2bf(a[2] + qb[o0g + 2]);
                pk.w = f2bf(a[3] + qb[o0g + 3]);
                *(ushort4*)(dstT + (size_t)b * NTOK * CH + (size_t)col * CH + ro) = pk;
            } else {
#pragma unroll
                for (int r = 0; r < 4; r++)
                    V[(size_t)b * CH * NTOK + (size_t)(ro + r) * NTOK + col] = f2bf(a[r] + qb[o0g + r]);
            }
        }
    }
}

// ---------------- GEMM2: S[n][m] bf16 = scale * Q·K^T ----------------
__global__ __launch_bounds__(256) void k_gemm_sc(const unsigned short* __restrict__ QT,
                                                 const unsigned short* __restrict__ KT,
                                                 unsigned short* __restrict__ S) {
    __shared__ __align__(16) unsigned short sA[128 * 32];
    __shared__ __align__(16) unsigned short sB[128 * 32];
    const int b  = blockIdx.z;
    const int m0 = blockIdx.y * 128;  // n
    const int n0 = blockIdx.x * 128;  // m
    f32x4 acc[4][4];
    mfma_core(QT + (size_t)b * NTOK * CH, CH, KT + (size_t)b * NTOK * CH, CH, CH, m0, n0, sA, sB, acc);
    const int t = threadIdx.x;
    const int w = t >> 6, lane = t & 63;
    const int wm = (w & 1) * 64, wn = (w >> 1) * 64;
    const int r16 = lane & 15, quad = lane >> 4;
    const float scale = 0.044194173824159216f;  // 512^-0.5
    unsigned short* Sb = S + (size_t)b * NTOK * NTOK;
#pragma unroll
    for (int i = 0; i < 4; i++) {
        const int row0 = m0 + wm + i * 16 + quad * 4;
#pragma unroll
        for (int j = 0; j < 4; j++) {
            const int col = n0 + wn + j * 16 + r16;
            f32x4 a = acc[i][j];
#pragma unroll
            for (int r = 0; r < 4; r++)
                Sb[(size_t)(row0 + r) * NTOK + col] = f2bf(a[r] * scale);
        }
    }
}

// ---------------- softmax: S bf16 row -> P bf16 row ----------------
__global__ __launch_bounds__(256) void k_softmax(const unsigned short* __restrict__ S, unsigned short* __restrict__ P) {
    size_t row = blockIdx.x;
    const unsigned short* p = S + row * NTOK;
    unsigned short* q = P + row * NTOK;
    int t = threadIdx.x;
    int wave = t >> 6, lane = t & 63;
    __shared__ float red[4];
    ushort4 u = ((const ushort4*)p)[t];
    float4 v;
    v.x = bf2f(u.x); v.y = bf2f(u.y); v.z = bf2f(u.z); v.w = bf2f(u.w);
    float m = fmaxf(fmaxf(v.x, v.y), fmaxf(v.z, v.w));
#pragma unroll
    for (int off = 32; off; off >>= 1) m = fmaxf(m, __shfl_xor(m, off, 64));
    if (lane == 0) red[wave] = m;
    __syncthreads();
    m = fmaxf(fmaxf(red[0], red[1]), fmaxf(red[2], red[3]));
    __syncthreads();
    v.x = __expf(v.x - m);
    v.y = __expf(v.y - m);
    v.z = __expf(v.z - m);
    v.w = __expf(v.w - m);
    float s = v.x + v.y + v.z + v.w;
#pragma unroll
    for (int off = 32; off; off >>= 1) s += __shfl_xor(s, off, 64);
    if (lane == 0) red[wave] = s;
    __syncthreads();
    s = red[0] + red[1] + red[2] + red[3];
    float inv = 1.0f / s;
    ushort4 o;
    o.x = f2bf(v.x * inv); o.y = f2bf(v.y * inv); o.z = f2bf(v.z * inv); o.w = f2bf(v.w * inv);
    ((ushort4*)q)[t] = o;
}

// ---------------- GEMM3: O[c][n] = V·P^T; store O_t[n][c] bf16 ----------------
__global__ __launch_bounds__(256) void k_gemm_av(const unsigned short* __restrict__ V,
                                                 const unsigned short* __restrict__ P,
                                                 unsigned short* __restrict__ OT) {
    __shared__ __align__(16) unsigned short sA[128 * 32];
    __shared__ __align__(16) unsigned short sB[128 * 32];
    const int b  = blockIdx.z;
    const int m0 = blockIdx.y * 128;  // c
    const int n0 = blockIdx.x * 128;  // n
    f32x4 acc[4][4];
    mfma_core(V + (size_t)b * CH * NTOK, NTOK, P + (size_t)b * NTOK * NTOK, NTOK, NTOK, m0, n0, sA, sB, acc);
    const int t = threadIdx.x;
    const int w = t >> 6, lane = t & 63;
    const int wm = (w & 1) * 64, wn = (w >> 1) * 64;
    const int r16 = lane & 15, quad = lane >> 4;
    unsigned short* OTb = OT + (size_t)b * NTOK * CH;
#pragma unroll
    for (int i = 0; i < 4; i++) {
        const int c0g = m0 + wm + i * 16 + quad * 4;
#pragma unroll
        for (int j = 0; j < 4; j++) {
            const int col = n0 + wn + j * 16 + r16;   // n
            f32x4 a = acc[i][j];
            ushort4 pk;
            pk.x = f2bf(a[0]); pk.y = f2bf(a[1]); pk.z = f2bf(a[2]); pk.w = f2bf(a[3]);
            *(ushort4*)(OTb + (size_t)col * CH + c0g) = pk;
        }
    }
}

// ---------------- GEMM4: out = OW·O + ob + x ----------------
__global__ __launch_bounds__(256) void k_gemm_out(const unsigned short* __restrict__ OW,
                                                  const float* __restrict__ ob,
                                                  const unsigned short* __restrict__ OT,
                                                  const float* __restrict__ x,
                                                  float* __restrict__ out) {
    __shared__ __align__(16) unsigned short sA[128 * 32];
    __shared__ __align__(16) unsigned short sB[128 * 32];
    const int b  = blockIdx.z;
    const int m0 = blockIdx.y * 128;  // o
    const int n0 = blockIdx.x * 128;  // n
    f32x4 acc[4][4];
    mfma_core(OW, CH, OT + (size_t)b * NTOK * CH, CH, CH, m0, n0, sA, sB, acc);
    const int t = threadIdx.x;
    const int w = t >> 6, lane = t & 63;
    const int wm = (w & 1) * 64, wn = (w >> 1) * 64;
    const int r16 = lane & 15, quad = lane >> 4;
#pragma unroll
    for (int i = 0; i < 4; i++) {
        const int o0g = m0 + wm + i * 16 + quad * 4;
#pragma unroll
        for (int j = 0; j < 4; j++) {
            const int col = n0 + wn + j * 16 + r16;
            f32x4 a = acc[i][j];
#pragma unroll
            for (int r = 0; r < 4; r++) {
                size_t idx = (size_t)b * CHW + (size_t)(o0g + r) * NTOK + col;
                out[idx] = a[r] + ob[o0g + r] + x[idx];
            }
        }
    }
}

extern "C" void kernel_launch(void* const* d_in, const int* in_sizes, int n_in,
                              void* d_out, int out_size, void* d_ws, size_t ws_size,
                              hipStream_t stream) {
    const float* x      = (const float*)d_in[0];
    const float* norm_w = (const float*)d_in[1];
    const float* norm_b = (const float*)d_in[2];
    const float* qkv_w  = (const float*)d_in[3];
    const float* qkv_b  = (const float*)d_in[4];
    const float* out_w  = (const float*)d_in[5];
    const float* out_b  = (const float*)d_in[6];
    float* out = (float*)d_out;
    char* wsb  = (char*)d_ws;

    float* stats = (float*)wsb;
    unsigned short* WQ  = (unsigned short*)(wsb + OFF_WQKV);
    unsigned short* OW  = (unsigned short*)(wsb + OFF_OW);
    unsigned short* XNT = (unsigned short*)(wsb + OFF_XNT);
    unsigned short* QT  = (unsigned short*)(wsb + OFF_QT);
    unsigned short* KT  = (unsigned short*)(wsb + OFF_KT);
    unsigned short* V   = (unsigned short*)(wsb + OFF_V);
    unsigned short* OT  = (unsigned short*)(wsb + OFF_OT);
    unsigned short* S   = (unsigned short*)(wsb + OFF_S);
    unsigned short* P   = (unsigned short*)(wsb + OFF_P);

    k_zero_stats<<<1, 64, 0, stream>>>(stats);
    k_stats_partial<<<BATCH * 64, 256, 0, stream>>>(x, stats);
    k_stats_final<<<1, 16, 0, stream>>>(stats);
    k_cvt<<<768, 256, 0, stream>>>(qkv_w, WQ, 3 * CH * CH / 4);
    k_cvt<<<256, 256, 0, stream>>>(out_w, OW, CH * CH / 4);
    k_xnt<<<dim3(NTOK / 64, CH / 64, BATCH), 256, 0, stream>>>(x, norm_w, norm_b, stats, XNT);
    k_gemm_qkv<<<dim3(NTOK / 128, 3 * CH / 128, BATCH), 256, 0, stream>>>(WQ, qkv_b, XNT, QT, KT, V);
    k_gemm_sc<<<dim3(NTOK / 128, NTOK / 128, BATCH), 256, 0, stream>>>(QT, KT, S);
    k_softmax<<<BATCH * NTOK, 256, 0, stream>>>(S, P);
    k_gemm_av<<<dim3(NTOK / 128, CH / 128, BATCH), 256, 0, stream>>>(V, P, OT);
    k_gemm_out<<<dim3(NTOK / 128, CH / 128, BATCH), 256, 0, stream>>>(OW, out_b, OT, x, out);
}

// Round 4
// 258.632 us; speedup vs baseline: 5.6167x; 1.0292x over previous
//
#include <hip/hip_runtime.h>
#include <math.h>

#define BATCH 16
#define CH    512
#define NTOK  1024
#define CHW   (CH * NTOK)
#define EPSV  1e-5f

typedef __attribute__((ext_vector_type(8))) short bf16x8;
typedef __attribute__((ext_vector_type(4))) float f32x4;

__device__ __forceinline__ unsigned short f2bf(float f) {
    union { float f; unsigned u; } cv; cv.f = f;
    unsigned r = cv.u + 0x7FFFu + ((cv.u >> 16) & 1u);   // round-to-nearest-even
    return (unsigned short)(r >> 16);
}
__device__ __forceinline__ float bf2f(unsigned short u) {
    union { unsigned u; float f; } cv; cv.u = ((unsigned)u) << 16;
    return cv.f;
}

// async global -> LDS, 16 bytes per lane. LDS dest = wave-uniform base + lane*16.
__device__ __forceinline__ void async16(const unsigned short* g, unsigned short* l) {
    __builtin_amdgcn_global_load_lds(
        (const __attribute__((address_space(1))) void*)g,
        (__attribute__((address_space(3))) void*)l,
        16, 0, 0);
}

// ---------------- workspace layout (byte offsets) ----------------
static const size_t OFF_WQKV = 256;                        // 1536*512 bf16
static const size_t OFF_OW   = OFF_WQKV + 1572864;         // 512*512 bf16
static const size_t OFF_XNT  = OFF_OW   + 524288;          // B*N*C bf16 (xn token-major)
static const size_t OFF_QT   = OFF_XNT  + 16777216;        // B*N*C bf16
static const size_t OFF_KT   = OFF_QT   + 16777216;        // B*N*C bf16
static const size_t OFF_V    = OFF_KT   + 16777216;        // B*C*N bf16 (channel-major)
static const size_t OFF_OT   = OFF_V    + 16777216;        // B*N*C bf16
static const size_t OFF_S    = OFF_OT   + 16777216;        // B*N*N bf16 (scores)
static const size_t OFF_P    = OFF_S    + 33554432;        // B*N*N bf16 (probs)

// ---------------- stats ----------------
__global__ void k_zero_stats(float* ws) {
    if (threadIdx.x < 64) ws[threadIdx.x] = 0.0f;
}

__global__ __launch_bounds__(256) void k_stats_partial(const float* __restrict__ x, float* __restrict__ ws) {
    int blk   = blockIdx.x;
    int b     = blk >> 6;
    int chunk = blk & 63;
    const float4* xp = (const float4*)(x + (size_t)b * CHW + (size_t)chunk * 8192);
    int t = threadIdx.x;
    float s = 0.0f, ss = 0.0f;
#pragma unroll
    for (int j = 0; j < 8; j++) {
        float4 v = xp[t + j * 256];
        s  += v.x + v.y + v.z + v.w;
        ss += v.x * v.x + v.y * v.y + v.z * v.z + v.w * v.w;
    }
#pragma unroll
    for (int off = 32; off; off >>= 1) {
        s  += __shfl_xor(s, off, 64);
        ss += __shfl_xor(ss, off, 64);
    }
    __shared__ float ls[4], lss[4];
    int wave = t >> 6, lane = t & 63;
    if (lane == 0) { ls[wave] = s; lss[wave] = ss; }
    __syncthreads();
    if (t == 0) {
        atomicAdd(&ws[b], ls[0] + ls[1] + ls[2] + ls[3]);
        atomicAdd(&ws[16 + b], lss[0] + lss[1] + lss[2] + lss[3]);
    }
}

__global__ void k_stats_final(float* ws) {
    int b = threadIdx.x;
    if (b < 16) {
        float inv  = 1.0f / (float)CHW;
        float mean = ws[b] * inv;
        float var  = ws[16 + b] * inv - mean * mean;
        ws[32 + b] = mean;
        ws[48 + b] = rsqrtf(var + EPSV);
    }
}

// ---------------- weight f32 -> bf16 ----------------
__global__ __launch_bounds__(256) void k_cvt(const float* __restrict__ in, unsigned short* __restrict__ out, int n4) {
    int i = blockIdx.x * 256 + threadIdx.x;
    if (i < n4) {
        float4 v = ((const float4*)in)[i];
        ushort4 o;
        o.x = f2bf(v.x); o.y = f2bf(v.y); o.z = f2bf(v.z); o.w = f2bf(v.w);
        ((ushort4*)out)[i] = o;
    }
}

// ---------------- normalize + transpose -> xn_t[b][n][c] bf16 ----------------
__global__ __launch_bounds__(256) void k_xnt(const float* __restrict__ x,
                                             const float* __restrict__ nw,
                                             const float* __restrict__ nb,
                                             const float* __restrict__ ws,
                                             unsigned short* __restrict__ xnt) {
    __shared__ float ls[64][65];
    int b  = blockIdx.z;
    int c0 = blockIdx.y * 64;
    int n0 = blockIdx.x * 64;
    float mean = ws[32 + b], rstd = ws[48 + b];
    int t = threadIdx.x;
    int cl = t >> 4, n4 = t & 15;
    const float* xb = x + (size_t)b * CHW;
#pragma unroll
    for (int i = 0; i < 4; i++) {
        int c = c0 + cl + i * 16;
        float a  = rstd * nw[c];
        float bb = nb[c] - mean * a;
        float4 v = *(const float4*)(xb + (size_t)c * NTOK + n0 + n4 * 4);
        ls[cl + i * 16][n4 * 4 + 0] = v.x * a + bb;
        ls[cl + i * 16][n4 * 4 + 1] = v.y * a + bb;
        ls[cl + i * 16][n4 * 4 + 2] = v.z * a + bb;
        ls[cl + i * 16][n4 * 4 + 3] = v.w * a + bb;
    }
    __syncthreads();
    int nl = t >> 4, c4 = t & 15;
    unsigned short* dst = xnt + (size_t)b * NTOK * CH;
#pragma unroll
    for (int i = 0; i < 4; i++) {
        int n = n0 + nl + i * 16;
        ushort4 o;
        o.x = f2bf(ls[c4 * 4 + 0][nl + i * 16]);
        o.y = f2bf(ls[c4 * 4 + 1][nl + i * 16]);
        o.z = f2bf(ls[c4 * 4 + 2][nl + i * 16]);
        o.w = f2bf(ls[c4 * 4 + 3][nl + i * 16]);
        *(ushort4*)(dst + (size_t)n * CH + c0 + c4 * 4) = o;
    }
}

// ---------------- MFMA GEMM core, double-buffered async staging ----------------
// D[m][n] = sum_k A[m][k] * B[n][k]  (both k-contiguous bf16)
// 256 thr = 4 waves, 128x128 tile, BK=32.
// smem layout: A bufs [0,4096),[4096,8192); B bufs [8192,12288),[12288,16384)
__device__ __forceinline__ void mfma_core(const unsigned short* __restrict__ A, int lda,
                                          const unsigned short* __restrict__ B, int ldb,
                                          int K, int m0, int n0,
                                          unsigned short* sm,
                                          f32x4 acc[4][4]) {
    const int t = threadIdx.x;
    const int w = t >> 6, lane = t & 63;
    const int wm = (w & 1) * 64, wn = (w >> 1) * 64;
    const int r16 = lane & 15, quad = lane >> 4;
#pragma unroll
    for (int i = 0; i < 4; i++)
#pragma unroll
        for (int j = 0; j < 4; j++) acc[i][j] = (f32x4){0.f, 0.f, 0.f, 0.f};
    const int sr = lane >> 2;           // row within 16-row chunk
    const int sk = (lane & 3) * 8;      // k element offset (16B)
    const unsigned short* gA0 = A + (size_t)(m0 + w * 32 + sr) * lda + sk;
    const unsigned short* gA1 = gA0 + (size_t)16 * lda;
    const unsigned short* gB0 = B + (size_t)(n0 + w * 32 + sr) * ldb + sk;
    const unsigned short* gB1 = gB0 + (size_t)16 * ldb;
    unsigned short* lA0 = sm + (w * 32) * 32;
    unsigned short* lA1 = sm + (w * 32 + 16) * 32;
    unsigned short* lB0 = sm + 8192 + (w * 32) * 32;
    unsigned short* lB1 = sm + 8192 + (w * 32 + 16) * 32;
    const int T = K >> 5;
    // prologue: stage tile 0 into buffer 0
    async16(gA0, lA0);
    async16(gA1, lA1);
    async16(gB0, lB0);
    async16(gB1, lB1);
    for (int tt = 0; tt < T; tt++) {
        __syncthreads();                     // drains stage(tt); guards buffer reuse
        const int cur = (tt & 1) << 12;      // 0 or 4096
        if (tt + 1 < T) {
            const int nxt = cur ^ 4096;
            const int ko = (tt + 1) << 5;
            async16(gA0 + ko, lA0 + nxt);
            async16(gA1 + ko, lA1 + nxt);
            async16(gB0 + ko, lB0 + nxt);
            async16(gB1 + ko, lB1 + nxt);
        }
        bf16x8 af[4], bfr[4];
#pragma unroll
        for (int i = 0; i < 4; i++) af[i]  = *(const bf16x8*)(sm + cur + (wm + i * 16 + r16) * 32 + quad * 8);
#pragma unroll
        for (int j = 0; j < 4; j++) bfr[j] = *(const bf16x8*)(sm + 8192 + cur + (wn + j * 16 + r16) * 32 + quad * 8);
#pragma unroll
        for (int i = 0; i < 4; i++)
#pragma unroll
            for (int j = 0; j < 4; j++)
                acc[i][j] = __builtin_amdgcn_mfma_f32_16x16x32_bf16(af[i], bfr[j], acc[i][j], 0, 0, 0);
    }
}

#define TSTRIDE 136   // padded ushort stride for 128-wide transpose tile

// ---------------- GEMM1: qkv; coalesced stores via LDS transpose ----------------
__global__ __launch_bounds__(256) void k_gemm_qkv(const unsigned short* __restrict__ Wq,
                                                  const float* __restrict__ qb,
                                                  const unsigned short* __restrict__ XNT,
                                                  unsigned short* __restrict__ QT,
                                                  unsigned short* __restrict__ KT,
                                                  unsigned short* __restrict__ V) {
    __shared__ __align__(16) unsigned short smem[128 * TSTRIDE];   // >= 16384 staging
    const int b  = blockIdx.z;
    const int m0 = blockIdx.y * 128;  // o in [0,1536)
    const int n0 = blockIdx.x * 128;  // n
    f32x4 acc[4][4];
    mfma_core(Wq, CH, XNT + (size_t)b * NTOK * CH, CH, CH, m0, n0, smem, acc);
    const int t = threadIdx.x;
    const int w = t >> 6, lane = t & 63;
    const int wm = (w & 1) * 64, wn = (w >> 1) * 64;
    const int r16 = lane & 15, quad = lane >> 4;
    const int region = m0 >> 9;  // 0=Q 1=K 2=V (block-uniform)
    __syncthreads();             // all waves done with staging LDS
    if (region < 2) {
        // tile rows = n_local, cols = o_local (token-major dst)
#pragma unroll
        for (int i = 0; i < 4; i++) {
            const int ol = wm + i * 16 + quad * 4;
            const int og = m0 + ol;
            const float b0 = qb[og], b1 = qb[og + 1], b2 = qb[og + 2], b3 = qb[og + 3];
#pragma unroll
            for (int j = 0; j < 4; j++) {
                const int nl = wn + j * 16 + r16;
                f32x4 a = acc[i][j];
                ushort4 pk;
                pk.x = f2bf(a[0] + b0); pk.y = f2bf(a[1] + b1);
                pk.z = f2bf(a[2] + b2); pk.w = f2bf(a[3] + b3);
                *(ushort4*)(smem + nl * TSTRIDE + ol) = pk;
            }
        }
        __syncthreads();
        unsigned short* dst = ((region == 0) ? QT : KT) + (size_t)b * NTOK * CH + (size_t)n0 * CH + (m0 & 511);
#pragma unroll
        for (int p = 0; p < 16; p++) {
            const int row = (t >> 5) + p * 8;
            const int seg = (t & 31) * 4;
            *(ushort4*)(dst + (size_t)row * CH + seg) = *(const ushort4*)(smem + row * TSTRIDE + seg);
        }
    } else {
        // tile rows = o_local, cols = n_local (channel-major dst)
#pragma unroll
        for (int i = 0; i < 4; i++) {
            const int ol = wm + i * 16 + quad * 4;
            const int og = m0 + ol;
#pragma unroll
            for (int j = 0; j < 4; j++) {
                const int nl = wn + j * 16 + r16;
                f32x4 a = acc[i][j];
#pragma unroll
                for (int r = 0; r < 4; r++)
                    smem[(ol + r) * TSTRIDE + nl] = f2bf(a[r] + qb[og + r]);
            }
        }
        __syncthreads();
        unsigned short* dst = V + (size_t)b * CH * NTOK + (size_t)(m0 & 511) * NTOK + n0;
#pragma unroll
        for (int p = 0; p < 16; p++) {
            const int row = (t >> 5) + p * 8;
            const int seg = (t & 31) * 4;
            *(ushort4*)(dst + (size_t)row * NTOK + seg) = *(const ushort4*)(smem + row * TSTRIDE + seg);
        }
    }
}

// ---------------- GEMM2: S[n][m] bf16 = scale * Q·K^T ----------------
__global__ __launch_bounds__(256) void k_gemm_sc(const unsigned short* __restrict__ QT,
                                                 const unsigned short* __restrict__ KT,
                                                 unsigned short* __restrict__ S) {
    __shared__ __align__(16) unsigned short smem[16384];
    const int b  = blockIdx.z;
    const int m0 = blockIdx.y * 128;  // n
    const int n0 = blockIdx.x * 128;  // m
    f32x4 acc[4][4];
    mfma_core(QT + (size_t)b * NTOK * CH, CH, KT + (size_t)b * NTOK * CH, CH, CH, m0, n0, smem, acc);
    const int t = threadIdx.x;
    const int w = t >> 6, lane = t & 63;
    const int wm = (w & 1) * 64, wn = (w >> 1) * 64;
    const int r16 = lane & 15, quad = lane >> 4;
    const float scale = 0.044194173824159216f;  // 512^-0.5
    unsigned short* Sb = S + (size_t)b * NTOK * NTOK;
#pragma unroll
    for (int i = 0; i < 4; i++) {
        const int row0 = m0 + wm + i * 16 + quad * 4;
#pragma unroll
        for (int j = 0; j < 4; j++) {
            const int col = n0 + wn + j * 16 + r16;
            f32x4 a = acc[i][j];
#pragma unroll
            for (int r = 0; r < 4; r++)
                Sb[(size_t)(row0 + r) * NTOK + col] = f2bf(a[r] * scale);
        }
    }
}

// ---------------- softmax: S bf16 row -> P bf16 row ----------------
__global__ __launch_bounds__(256) void k_softmax(const unsigned short* __restrict__ S, unsigned short* __restrict__ P) {
    size_t row = blockIdx.x;
    const unsigned short* p = S + row * NTOK;
    unsigned short* q = P + row * NTOK;
    int t = threadIdx.x;
    int wave = t >> 6, lane = t & 63;
    __shared__ float red[4];
    ushort4 u = ((const ushort4*)p)[t];
    float4 v;
    v.x = bf2f(u.x); v.y = bf2f(u.y); v.z = bf2f(u.z); v.w = bf2f(u.w);
    float m = fmaxf(fmaxf(v.x, v.y), fmaxf(v.z, v.w));
#pragma unroll
    for (int off = 32; off; off >>= 1) m = fmaxf(m, __shfl_xor(m, off, 64));
    if (lane == 0) red[wave] = m;
    __syncthreads();
    m = fmaxf(fmaxf(red[0], red[1]), fmaxf(red[2], red[3]));
    __syncthreads();
    v.x = __expf(v.x - m);
    v.y = __expf(v.y - m);
    v.z = __expf(v.z - m);
    v.w = __expf(v.w - m);
    float s = v.x + v.y + v.z + v.w;
#pragma unroll
    for (int off = 32; off; off >>= 1) s += __shfl_xor(s, off, 64);
    if (lane == 0) red[wave] = s;
    __syncthreads();
    s = red[0] + red[1] + red[2] + red[3];
    float inv = 1.0f / s;
    ushort4 o;
    o.x = f2bf(v.x * inv); o.y = f2bf(v.y * inv); o.z = f2bf(v.z * inv); o.w = f2bf(v.w * inv);
    ((ushort4*)q)[t] = o;
}

// ---------------- GEMM3: O[c][n] = V·P^T; store O_t[n][c] via LDS transpose ----------------
__global__ __launch_bounds__(256) void k_gemm_av(const unsigned short* __restrict__ V,
                                                 const unsigned short* __restrict__ P,
                                                 unsigned short* __restrict__ OT) {
    __shared__ __align__(16) unsigned short smem[128 * TSTRIDE];
    const int b  = blockIdx.z;
    const int m0 = blockIdx.y * 128;  // c
    const int n0 = blockIdx.x * 128;  // n
    f32x4 acc[4][4];
    mfma_core(V + (size_t)b * CH * NTOK, NTOK, P + (size_t)b * NTOK * NTOK, NTOK, NTOK, m0, n0, smem, acc);
    const int t = threadIdx.x;
    const int w = t >> 6, lane = t & 63;
    const int wm = (w & 1) * 64, wn = (w >> 1) * 64;
    const int r16 = lane & 15, quad = lane >> 4;
    __syncthreads();
#pragma unroll
    for (int i = 0; i < 4; i++) {
        const int cl = wm + i * 16 + quad * 4;
#pragma unroll
        for (int j = 0; j < 4; j++) {
            const int nl = wn + j * 16 + r16;
            f32x4 a = acc[i][j];
            ushort4 pk;
            pk.x = f2bf(a[0]); pk.y = f2bf(a[1]); pk.z = f2bf(a[2]); pk.w = f2bf(a[3]);
            *(ushort4*)(smem + nl * TSTRIDE + cl) = pk;
        }
    }
    __syncthreads();
    unsigned short* dst = OT + (size_t)b * NTOK * CH + (size_t)n0 * CH + m0;
#pragma unroll
    for (int p = 0; p < 16; p++) {
        const int row = (t >> 5) + p * 8;
        const int seg = (t & 31) * 4;
        *(ushort4*)(dst + (size_t)row * CH + seg) = *(const ushort4*)(smem + row * TSTRIDE + seg);
    }
}

// ---------------- GEMM4: out = OW·O + ob + x ----------------
__global__ __launch_bounds__(256) void k_gemm_out(const unsigned short* __restrict__ OW,
                                                  const float* __restrict__ ob,
                                                  const unsigned short* __restrict__ OT,
                                                  const float* __restrict__ x,
                                                  float* __restrict__ out) {
    __shared__ __align__(16) unsigned short smem[16384];
    const int b  = blockIdx.z;
    const int m0 = blockIdx.y * 128;  // o
    const int n0 = blockIdx.x * 128;  // n
    f32x4 acc[4][4];
    mfma_core(OW, CH, OT + (size_t)b * NTOK * CH, CH, CH, m0, n0, smem, acc);
    const int t = threadIdx.x;
    const int w = t >> 6, lane = t & 63;
    const int wm = (w & 1) * 64, wn = (w >> 1) * 64;
    const int r16 = lane & 15, quad = lane >> 4;
#pragma unroll
    for (int i = 0; i < 4; i++) {
        const int o0g = m0 + wm + i * 16 + quad * 4;
#pragma unroll
        for (int j = 0; j < 4; j++) {
            const int col = n0 + wn + j * 16 + r16;
            f32x4 a = acc[i][j];
#pragma unroll
            for (int r = 0; r < 4; r++) {
                size_t idx = (size_t)b * CHW + (size_t)(o0g + r) * NTOK + col;
                out[idx] = a[r] + ob[o0g + r] + x[idx];
            }
        }
    }
}

extern "C" void kernel_launch(void* const* d_in, const int* in_sizes, int n_in,
                              void* d_out, int out_size, void* d_ws, size_t ws_size,
                              hipStream_t stream) {
    const float* x      = (const float*)d_in[0];
    const float* norm_w = (const float*)d_in[1];
    const float* norm_b = (const float*)d_in[2];
    const float* qkv_w  = (const float*)d_in[3];
    const float* qkv_b  = (const float*)d_in[4];
    const float* out_w  = (const float*)d_in[5];
    const float* out_b  = (const float*)d_in[6];
    float* out = (float*)d_out;
    char* wsb  = (char*)d_ws;

    float* stats = (float*)wsb;
    unsigned short* WQ  = (unsigned short*)(wsb + OFF_WQKV);
    unsigned short* OW  = (unsigned short*)(wsb + OFF_OW);
    unsigned short* XNT = (unsigned short*)(wsb + OFF_XNT);
    unsigned short* QT  = (unsigned short*)(wsb + OFF_QT);
    unsigned short* KT  = (unsigned short*)(wsb + OFF_KT);
    unsigned short* V   = (unsigned short*)(wsb + OFF_V);
    unsigned short* OT  = (unsigned short*)(wsb + OFF_OT);
    unsigned short* S   = (unsigned short*)(wsb + OFF_S);
    unsigned short* P   = (unsigned short*)(wsb + OFF_P);

    k_zero_stats<<<1, 64, 0, stream>>>(stats);
    k_stats_partial<<<BATCH * 64, 256, 0, stream>>>(x, stats);
    k_stats_final<<<1, 16, 0, stream>>>(stats);
    k_cvt<<<768, 256, 0, stream>>>(qkv_w, WQ, 3 * CH * CH / 4);
    k_cvt<<<256, 256, 0, stream>>>(out_w, OW, CH * CH / 4);
    k_xnt<<<dim3(NTOK / 64, CH / 64, BATCH), 256, 0, stream>>>(x, norm_w, norm_b, stats, XNT);
    k_gemm_qkv<<<dim3(NTOK / 128, 3 * CH / 128, BATCH), 256, 0, stream>>>(WQ, qkv_b, XNT, QT, KT, V);
    k_gemm_sc<<<dim3(NTOK / 128, NTOK / 128, BATCH), 256, 0, stream>>>(QT, KT, S);
    k_softmax<<<BATCH * NTOK, 256, 0, stream>>>(S, P);
    k_gemm_av<<<dim3(NTOK / 128, CH / 128, BATCH), 256, 0, stream>>>(V, P, OT);
    k_gemm_out<<<dim3(NTOK / 128, CH / 128, BATCH), 256, 0, stream>>>(OW, out_b, OT, x, out);
}

// Round 5
// 245.580 us; speedup vs baseline: 5.9152x; 1.0531x over previous
//
#include <hip/hip_runtime.h>
#include <math.h>

#define BATCH 16
#define CH    512
#define NTOK  1024
#define CHW   (CH * NTOK)
#define EPSV  1e-5f

typedef __attribute__((ext_vector_type(8))) short bf16x8;
typedef __attribute__((ext_vector_type(4))) float f32x4;

__device__ __forceinline__ unsigned short f2bf(float f) {
    union { float f; unsigned u; } cv; cv.f = f;
    unsigned r = cv.u + 0x7FFFu + ((cv.u >> 16) & 1u);   // RNE
    return (unsigned short)(r >> 16);
}
__device__ __forceinline__ float bf2f(unsigned short u) {
    union { unsigned u; float f; } cv; cv.u = ((unsigned)u) << 16;
    return cv.f;
}

// async global -> LDS, 16 bytes/lane; LDS dest = wave-uniform base + lane*16.
__device__ __forceinline__ void async16(const unsigned short* g, unsigned short* l) {
    __builtin_amdgcn_global_load_lds(
        (const __attribute__((address_space(1))) void*)g,
        (__attribute__((address_space(3))) void*)l,
        16, 0, 0);
}

// ---------------- workspace layout (byte offsets) ----------------
static const size_t OFF_WQKV = 256;                        // 1536*512 bf16
static const size_t OFF_OW   = OFF_WQKV + 1572864;         // 512*512 bf16
static const size_t OFF_XNT  = OFF_OW   + 524288;          // B*N*C bf16 (xn token-major)
static const size_t OFF_QT   = OFF_XNT  + 16777216;        // B*N*C bf16
static const size_t OFF_KT   = OFF_QT   + 16777216;        // B*N*C bf16
static const size_t OFF_V    = OFF_KT   + 16777216;        // B*C*N bf16 (channel-major)
static const size_t OFF_OT   = OFF_V    + 16777216;        // B*N*C bf16
static const size_t OFF_S    = OFF_OT   + 16777216;        // B*N*N bf16
static const size_t OFF_P    = OFF_S    + 33554432;        // B*N*N bf16

// ---------------- stats ----------------
__global__ void k_zero_stats(float* ws) {
    if (threadIdx.x < 64) ws[threadIdx.x] = 0.0f;
}

__global__ __launch_bounds__(256) void k_stats_partial(const float* __restrict__ x, float* __restrict__ ws) {
    int blk   = blockIdx.x;
    int b     = blk >> 6;
    int chunk = blk & 63;
    const float4* xp = (const float4*)(x + (size_t)b * CHW + (size_t)chunk * 8192);
    int t = threadIdx.x;
    float s = 0.0f, ss = 0.0f;
#pragma unroll
    for (int j = 0; j < 8; j++) {
        float4 v = xp[t + j * 256];
        s  += v.x + v.y + v.z + v.w;
        ss += v.x * v.x + v.y * v.y + v.z * v.z + v.w * v.w;
    }
#pragma unroll
    for (int off = 32; off; off >>= 1) {
        s  += __shfl_xor(s, off, 64);
        ss += __shfl_xor(ss, off, 64);
    }
    __shared__ float ls[4], lss[4];
    int wave = t >> 6, lane = t & 63;
    if (lane == 0) { ls[wave] = s; lss[wave] = ss; }
    __syncthreads();
    if (t == 0) {
        atomicAdd(&ws[b], ls[0] + ls[1] + ls[2] + ls[3]);
        atomicAdd(&ws[16 + b], lss[0] + lss[1] + lss[2] + lss[3]);
    }
}

__global__ void k_stats_final(float* ws) {
    int b = threadIdx.x;
    if (b < 16) {
        float inv  = 1.0f / (float)CHW;
        float mean = ws[b] * inv;
        float var  = ws[16 + b] * inv - mean * mean;
        ws[32 + b] = mean;
        ws[48 + b] = rsqrtf(var + EPSV);
    }
}

// ---------------- both weights f32 -> bf16 in one launch ----------------
__global__ __launch_bounds__(256) void k_cvt2(const float* __restrict__ wq, const float* __restrict__ wo,
                                              unsigned short* __restrict__ WQ, unsigned short* __restrict__ WO) {
    int i = blockIdx.x * 256 + threadIdx.x;   // float4 index, total 262144
    const float* src; unsigned short* dst; int off;
    if (i < 196608) { src = wq; dst = WQ; off = i; }
    else            { src = wo; dst = WO; off = i - 196608; }
    float4 v = ((const float4*)src)[off];
    ushort4 o;
    o.x = f2bf(v.x); o.y = f2bf(v.y); o.z = f2bf(v.z); o.w = f2bf(v.w);
    ((ushort4*)dst)[off] = o;
}

// ---------------- normalize + transpose -> xn_t[b][n][c] bf16 ----------------
__global__ __launch_bounds__(256) void k_xnt(const float* __restrict__ x,
                                             const float* __restrict__ nw,
                                             const float* __restrict__ nb,
                                             const float* __restrict__ ws,
                                             unsigned short* __restrict__ xnt) {
    __shared__ float ls[64][65];
    int b  = blockIdx.z;
    int c0 = blockIdx.y * 64;
    int n0 = blockIdx.x * 64;
    float mean = ws[32 + b], rstd = ws[48 + b];
    int t = threadIdx.x;
    int cl = t >> 4, n4 = t & 15;
    const float* xb = x + (size_t)b * CHW;
#pragma unroll
    for (int i = 0; i < 4; i++) {
        int c = c0 + cl + i * 16;
        float a  = rstd * nw[c];
        float bb = nb[c] - mean * a;
        float4 v = *(const float4*)(xb + (size_t)c * NTOK + n0 + n4 * 4);
        ls[cl + i * 16][n4 * 4 + 0] = v.x * a + bb;
        ls[cl + i * 16][n4 * 4 + 1] = v.y * a + bb;
        ls[cl + i * 16][n4 * 4 + 2] = v.z * a + bb;
        ls[cl + i * 16][n4 * 4 + 3] = v.w * a + bb;
    }
    __syncthreads();
    int nl = t >> 4, c4 = t & 15;
    unsigned short* dst = xnt + (size_t)b * NTOK * CH;
#pragma unroll
    for (int i = 0; i < 4; i++) {
        int n = n0 + nl + i * 16;
        ushort4 o;
        o.x = f2bf(ls[c4 * 4 + 0][nl + i * 16]);
        o.y = f2bf(ls[c4 * 4 + 1][nl + i * 16]);
        o.z = f2bf(ls[c4 * 4 + 2][nl + i * 16]);
        o.w = f2bf(ls[c4 * 4 + 3][nl + i * 16]);
        *(ushort4*)(dst + (size_t)n * CH + c0 + c4 * 4) = o;
    }
}

// ---------------- MFMA GEMM core: 128(M) x 256(N) block tile ----------------
// D[m][n] = sum_k A[m][k]*B[n][k], both k-contiguous bf16. 4 waves, each 64x128.
// LDS (shorts): A bufs [0,4096),[4096,8192); B bufs [8192,16384),[16384,24576)
__device__ __forceinline__ void mfma_core2(const unsigned short* __restrict__ A, int lda,
                                           const unsigned short* __restrict__ B, int ldb,
                                           int K, int m0, int n0,
                                           unsigned short* sm,
                                           f32x4 acc[4][8]) {
    const int t = threadIdx.x;
    const int w = t >> 6, lane = t & 63;
    const int wm = (w & 1) * 64, wn = (w >> 1) * 128;
    const int r16 = lane & 15, quad = lane >> 4;
#pragma unroll
    for (int i = 0; i < 4; i++)
#pragma unroll
        for (int j = 0; j < 8; j++) acc[i][j] = (f32x4){0.f, 0.f, 0.f, 0.f};
    const int sr = lane >> 2;
    const int sk = (lane & 3) * 8;
    const unsigned short* gA0 = A + (size_t)(m0 + w * 32 + sr) * lda + sk;
    const unsigned short* gA1 = gA0 + (size_t)16 * lda;
    const unsigned short* gB0 = B + (size_t)(n0 + w * 64 + sr) * ldb + sk;
    const unsigned short* gB1 = gB0 + (size_t)16 * ldb;
    const unsigned short* gB2 = gB0 + (size_t)32 * ldb;
    const unsigned short* gB3 = gB0 + (size_t)48 * ldb;
    unsigned short* lA0 = sm + (w * 32) * 32;
    unsigned short* lA1 = sm + (w * 32 + 16) * 32;
    unsigned short* lB0 = sm + 8192 + (w * 64) * 32;
    unsigned short* lB1 = lB0 + 16 * 32;
    unsigned short* lB2 = lB0 + 32 * 32;
    unsigned short* lB3 = lB0 + 48 * 32;
    const int T = K >> 5;
    async16(gA0, lA0); async16(gA1, lA1);
    async16(gB0, lB0); async16(gB1, lB1); async16(gB2, lB2); async16(gB3, lB3);
    for (int tt = 0; tt < T; tt++) {
        __syncthreads();
        const int ab = (tt & 1) << 12;   // 4096-short A buffers
        const int bb = (tt & 1) << 13;   // 8192-short B buffers
        if (tt + 1 < T) {
            const int nab = ab ^ 4096, nbb = bb ^ 8192;
            const int ko = (tt + 1) << 5;
            async16(gA0 + ko, lA0 + nab); async16(gA1 + ko, lA1 + nab);
            async16(gB0 + ko, lB0 + nbb); async16(gB1 + ko, lB1 + nbb);
            async16(gB2 + ko, lB2 + nbb); async16(gB3 + ko, lB3 + nbb);
        }
        bf16x8 af[4], bfr[8];
#pragma unroll
        for (int i = 0; i < 4; i++) af[i]  = *(const bf16x8*)(sm + ab + (wm + i * 16 + r16) * 32 + quad * 8);
#pragma unroll
        for (int j = 0; j < 8; j++) bfr[j] = *(const bf16x8*)(sm + 8192 + bb + (wn + j * 16 + r16) * 32 + quad * 8);
#pragma unroll
        for (int i = 0; i < 4; i++)
#pragma unroll
            for (int j = 0; j < 8; j++)
                acc[i][j] = __builtin_amdgcn_mfma_f32_16x16x32_bf16(af[i], bfr[j], acc[i][j], 0, 0, 0);
    }
}

#define TS1 136   // stride for [256][128] transpose tiles (rows=N)
#define TS2 264   // stride for [128][256] tiles (rows=M)

// ---------------- GEMM1: qkv ----------------
__global__ __launch_bounds__(256, 2) void k_gemm_qkv(const unsigned short* __restrict__ Wq,
                                                     const float* __restrict__ qb,
                                                     const unsigned short* __restrict__ XNT,
                                                     unsigned short* __restrict__ QT,
                                                     unsigned short* __restrict__ KT,
                                                     unsigned short* __restrict__ V) {
    __shared__ __align__(16) unsigned short smem[256 * TS1];   // 69632 B >= 49152 staging
    const int b  = blockIdx.z;
    const int m0 = blockIdx.y * 128;  // o in [0,1536)
    const int n0 = blockIdx.x * 256;  // n
    f32x4 acc[4][8];
    mfma_core2(Wq, CH, XNT + (size_t)b * NTOK * CH, CH, CH, m0, n0, smem, acc);
    const int t = threadIdx.x;
    const int w = t >> 6, lane = t & 63;
    const int wm = (w & 1) * 64, wn = (w >> 1) * 128;
    const int r16 = lane & 15, quad = lane >> 4;
    const int region = m0 >> 9;  // 0=Q 1=K 2=V (block-uniform)
    __syncthreads();
    if (region < 2) {
        // transpose tile: rows = n (256), cols = o (128)
#pragma unroll
        for (int i = 0; i < 4; i++) {
            const int ol = wm + i * 16 + quad * 4;
            const int og = m0 + ol;
            const float b0 = qb[og], b1 = qb[og + 1], b2 = qb[og + 2], b3 = qb[og + 3];
#pragma unroll
            for (int j = 0; j < 8; j++) {
                const int nl = wn + j * 16 + r16;
                f32x4 a = acc[i][j];
                ushort4 pk;
                pk.x = f2bf(a[0] + b0); pk.y = f2bf(a[1] + b1);
                pk.z = f2bf(a[2] + b2); pk.w = f2bf(a[3] + b3);
                *(ushort4*)(smem + nl * TS1 + ol) = pk;
            }
        }
        __syncthreads();
        unsigned short* dst = ((region == 0) ? QT : KT) + (size_t)b * NTOK * CH + (size_t)n0 * CH + (m0 & 511);
#pragma unroll
        for (int p = 0; p < 32; p++) {
            const int row = (t >> 5) + p * 8;           // 256 rows
            const int seg = (t & 31) * 4;               // 128 cols
            *(ushort4*)(dst + (size_t)row * CH + seg) = *(const ushort4*)(smem + row * TS1 + seg);
        }
    } else {
        // natural tile: rows = o (128), cols = n (256)
#pragma unroll
        for (int i = 0; i < 4; i++) {
            const int ol = wm + i * 16 + quad * 4;
            const int og = m0 + ol;
#pragma unroll
            for (int j = 0; j < 8; j++) {
                const int nl = wn + j * 16 + r16;
                f32x4 a = acc[i][j];
#pragma unroll
                for (int r = 0; r < 4; r++)
                    smem[(ol + r) * TS2 + nl] = f2bf(a[r] + qb[og + r]);
            }
        }
        __syncthreads();
        unsigned short* dst = V + (size_t)b * CH * NTOK + (size_t)(m0 & 511) * NTOK + n0;
#pragma unroll
        for (int p = 0; p < 32; p++) {
            const int row = (t >> 5) + (p & 15) * 8;    // 128 rows
            const int seg = (t & 31) * 4 + (p >> 4) * 128;  // 256 cols
            *(ushort4*)(dst + (size_t)row * NTOK + seg) = *(const ushort4*)(smem + row * TS2 + seg);
        }
    }
}

// ---------------- GEMM2: S[q][keys] bf16 = scale * Q·K^T ----------------
__global__ __launch_bounds__(256, 2) void k_gemm_sc(const unsigned short* __restrict__ QT,
                                                    const unsigned short* __restrict__ KT,
                                                    unsigned short* __restrict__ S) {
    __shared__ __align__(16) unsigned short smem[256 * TS1];
    const int b  = blockIdx.z;
    const int m0 = blockIdx.y * 128;  // q
    const int n0 = blockIdx.x * 256;  // keys
    f32x4 acc[4][8];
    mfma_core2(QT + (size_t)b * NTOK * CH, CH, KT + (size_t)b * NTOK * CH, CH, CH, m0, n0, smem, acc);
    const int t = threadIdx.x;
    const int w = t >> 6, lane = t & 63;
    const int wm = (w & 1) * 64, wn = (w >> 1) * 128;
    const int r16 = lane & 15, quad = lane >> 4;
    const float scale = 0.044194173824159216f;  // 512^-0.5
    __syncthreads();
#pragma unroll
    for (int i = 0; i < 4; i++) {
        const int ml = wm + i * 16 + quad * 4;
#pragma unroll
        for (int j = 0; j < 8; j++) {
            const int kl = wn + j * 16 + r16;
            f32x4 a = acc[i][j];
#pragma unroll
            for (int r = 0; r < 4; r++)
                smem[(ml + r) * TS2 + kl] = f2bf(a[r] * scale);
        }
    }
    __syncthreads();
    unsigned short* dst = S + (size_t)b * NTOK * NTOK + (size_t)m0 * NTOK + n0;
#pragma unroll
    for (int p = 0; p < 32; p++) {
        const int row = (t >> 5) + (p & 15) * 8;
        const int seg = (t & 31) * 4 + (p >> 4) * 128;
        *(ushort4*)(dst + (size_t)row * NTOK + seg) = *(const ushort4*)(smem + row * TS2 + seg);
    }
}

// ---------------- softmax: S bf16 row -> P bf16 row ----------------
__global__ __launch_bounds__(256) void k_softmax(const unsigned short* __restrict__ S, unsigned short* __restrict__ P) {
    size_t row = blockIdx.x;
    const unsigned short* p = S + row * NTOK;
    unsigned short* q = P + row * NTOK;
    int t = threadIdx.x;
    int wave = t >> 6, lane = t & 63;
    __shared__ float red[4];
    ushort4 u = ((const ushort4*)p)[t];
    float4 v;
    v.x = bf2f(u.x); v.y = bf2f(u.y); v.z = bf2f(u.z); v.w = bf2f(u.w);
    float m = fmaxf(fmaxf(v.x, v.y), fmaxf(v.z, v.w));
#pragma unroll
    for (int off = 32; off; off >>= 1) m = fmaxf(m, __shfl_xor(m, off, 64));
    if (lane == 0) red[wave] = m;
    __syncthreads();
    m = fmaxf(fmaxf(red[0], red[1]), fmaxf(red[2], red[3]));
    __syncthreads();
    v.x = __expf(v.x - m);
    v.y = __expf(v.y - m);
    v.z = __expf(v.z - m);
    v.w = __expf(v.w - m);
    float s = v.x + v.y + v.z + v.w;
#pragma unroll
    for (int off = 32; off; off >>= 1) s += __shfl_xor(s, off, 64);
    if (lane == 0) red[wave] = s;
    __syncthreads();
    s = red[0] + red[1] + red[2] + red[3];
    float inv = 1.0f / s;
    ushort4 o;
    o.x = f2bf(v.x * inv); o.y = f2bf(v.y * inv); o.z = f2bf(v.z * inv); o.w = f2bf(v.w * inv);
    ((ushort4*)q)[t] = o;
}

// ---------------- GEMM3: O[c][n] = V·P^T; store OT[n][c] ----------------
__global__ __launch_bounds__(256, 2) void k_gemm_av(const unsigned short* __restrict__ V,
                                                    const unsigned short* __restrict__ P,
                                                    unsigned short* __restrict__ OT) {
    __shared__ __align__(16) unsigned short smem[256 * TS1];
    const int b  = blockIdx.z;
    const int m0 = blockIdx.y * 128;  // c
    const int n0 = blockIdx.x * 256;  // n
    f32x4 acc[4][8];
    mfma_core2(V + (size_t)b * CH * NTOK, NTOK, P + (size_t)b * NTOK * NTOK, NTOK, NTOK, m0, n0, smem, acc);
    const int t = threadIdx.x;
    const int w = t >> 6, lane = t & 63;
    const int wm = (w & 1) * 64, wn = (w >> 1) * 128;
    const int r16 = lane & 15, quad = lane >> 4;
    __syncthreads();
#pragma unroll
    for (int i = 0; i < 4; i++) {
        const int cl = wm + i * 16 + quad * 4;
#pragma unroll
        for (int j = 0; j < 8; j++) {
            const int nl = wn + j * 16 + r16;
            f32x4 a = acc[i][j];
            ushort4 pk;
            pk.x = f2bf(a[0]); pk.y = f2bf(a[1]); pk.z = f2bf(a[2]); pk.w = f2bf(a[3]);
            *(ushort4*)(smem + nl * TS1 + cl) = pk;
        }
    }
    __syncthreads();
    unsigned short* dst = OT + (size_t)b * NTOK * CH + (size_t)n0 * CH + m0;
#pragma unroll
    for (int p = 0; p < 32; p++) {
        const int row = (t >> 5) + p * 8;       // 256 n rows
        const int seg = (t & 31) * 4;           // 128 c cols
        *(ushort4*)(dst + (size_t)row * CH + seg) = *(const ushort4*)(smem + row * TS1 + seg);
    }
}

// ---------------- GEMM4: out = OW·O + ob + x ----------------
__global__ __launch_bounds__(256, 2) void k_gemm_out(const unsigned short* __restrict__ OW,
                                                     const float* __restrict__ ob,
                                                     const unsigned short* __restrict__ OT,
                                                     const float* __restrict__ x,
                                                     float* __restrict__ out) {
    __shared__ __align__(16) unsigned short smem[24576];
    const int b  = blockIdx.z;
    const int m0 = blockIdx.y * 128;  // o
    const int n0 = blockIdx.x * 256;  // n
    f32x4 acc[4][8];
    mfma_core2(OW, CH, OT + (size_t)b * NTOK * CH, CH, CH, m0, n0, smem, acc);
    const int t = threadIdx.x;
    const int w = t >> 6, lane = t & 63;
    const int wm = (w & 1) * 64, wn = (w >> 1) * 128;
    const int r16 = lane & 15, quad = lane >> 4;
#pragma unroll
    for (int i = 0; i < 4; i++) {
        const int o0g = m0 + wm + i * 16 + quad * 4;
#pragma unroll
        for (int j = 0; j < 8; j++) {
            const int col = n0 + wn + j * 16 + r16;
            f32x4 a = acc[i][j];
#pragma unroll
            for (int r = 0; r < 4; r++) {
                size_t idx = (size_t)b * CHW + (size_t)(o0g + r) * NTOK + col;
                out[idx] = a[r] + ob[o0g + r] + x[idx];
            }
        }
    }
}

extern "C" void kernel_launch(void* const* d_in, const int* in_sizes, int n_in,
                              void* d_out, int out_size, void* d_ws, size_t ws_size,
                              hipStream_t stream) {
    const float* x      = (const float*)d_in[0];
    const float* norm_w = (const float*)d_in[1];
    const float* norm_b = (const float*)d_in[2];
    const float* qkv_w  = (const float*)d_in[3];
    const float* qkv_b  = (const float*)d_in[4];
    const float* out_w  = (const float*)d_in[5];
    const float* out_b  = (const float*)d_in[6];
    float* out = (float*)d_out;
    char* wsb  = (char*)d_ws;

    float* stats = (float*)wsb;
    unsigned short* WQ  = (unsigned short*)(wsb + OFF_WQKV);
    unsigned short* OW  = (unsigned short*)(wsb + OFF_OW);
    unsigned short* XNT = (unsigned short*)(wsb + OFF_XNT);
    unsigned short* QT  = (unsigned short*)(wsb + OFF_QT);
    unsigned short* KT  = (unsigned short*)(wsb + OFF_KT);
    unsigned short* V   = (unsigned short*)(wsb + OFF_V);
    unsigned short* OT  = (unsigned short*)(wsb + OFF_OT);
    unsigned short* S   = (unsigned short*)(wsb + OFF_S);
    unsigned short* P   = (unsigned short*)(wsb + OFF_P);

    k_zero_stats<<<1, 64, 0, stream>>>(stats);
    k_stats_partial<<<BATCH * 64, 256, 0, stream>>>(x, stats);
    k_stats_final<<<1, 16, 0, stream>>>(stats);
    k_cvt2<<<1024, 256, 0, stream>>>(qkv_w, out_w, WQ, OW);
    k_xnt<<<dim3(NTOK / 64, CH / 64, BATCH), 256, 0, stream>>>(x, norm_w, norm_b, stats, XNT);
    k_gemm_qkv<<<dim3(NTOK / 256, 3 * CH / 128, BATCH), 256, 0, stream>>>(WQ, qkv_b, XNT, QT, KT, V);
    k_gemm_sc<<<dim3(NTOK / 256, NTOK / 128, BATCH), 256, 0, stream>>>(QT, KT, S);
    k_softmax<<<BATCH * NTOK, 256, 0, stream>>>(S, P);
    k_gemm_av<<<dim3(NTOK / 256, CH / 128, BATCH), 256, 0, stream>>>(V, P, OT);
    k_gemm_out<<<dim3(NTOK / 256, CH / 128, BATCH), 256, 0, stream>>>(OW, out_b, OT, x, out);
}